// Round 1
// baseline (386.200 us; speedup 1.0000x reference)
//
#include <hip/hip_runtime.h>
#include <math.h>

#define TOKENS 32768
#define KCODES 8192
#define DIM 32
#define CHUNKS 8
#define CPC (KCODES / CHUNKS)       // 1024 codes per chunk
#define ZQ_ELEMS (TOKENS * DIM)     // 1048576

// ---------------------------------------------------------------------------
// Kernel 1: normalize embedding rows, compute per-row sum(e_n^2).
// 32 lanes per row; grid covers 8192*32 elements.
// ---------------------------------------------------------------------------
__global__ __launch_bounds__(256) void norm_emb_kernel(
    const float* __restrict__ emb, float* __restrict__ emb_n,
    float* __restrict__ nsq) {
  int t = blockIdx.x * 256 + threadIdx.x;  // element index, 0..262143
  int lane = threadIdx.x & 31;
  float v = emb[t];
  float s = v * v;
#pragma unroll
  for (int off = 16; off > 0; off >>= 1) s += __shfl_xor(s, off, 32);
  float r = 1.0f / sqrtf(s + 1e-12f);
  float vn = v * r;
  emb_n[t] = vn;
  float s2 = vn * vn;
#pragma unroll
  for (int off = 16; off > 0; off >>= 1) s2 += __shfl_xor(s2, off, 32);
  if (lane == 0) nsq[t >> 5] = s2;
}

// ---------------------------------------------------------------------------
// Kernel 2: per-token partial argmin over a chunk of 1024 codes.
// One token per thread; token vector (normalized) held in registers;
// embedding reads are wave-uniform -> scalar loads. Unroll-by-4 for ILP.
// ---------------------------------------------------------------------------
__global__ __launch_bounds__(256) void argmin_partial_kernel(
    const float* __restrict__ hs, const float* __restrict__ emb_n,
    const float* __restrict__ nsq, float* __restrict__ pdist,
    int* __restrict__ pidx) {
  int token = blockIdx.x * 256 + threadIdx.x;
  int chunk = blockIdx.y;

  float z[DIM];
  const float4* hp = (const float4*)(hs + (size_t)token * DIM);
  float ss = 0.f;
#pragma unroll
  for (int j = 0; j < 8; j++) {
    float4 q = hp[j];
    z[4 * j] = q.x; z[4 * j + 1] = q.y; z[4 * j + 2] = q.z; z[4 * j + 3] = q.w;
    ss += q.x * q.x + q.y * q.y + q.z * q.z + q.w * q.w;
  }
  float rz = 1.0f / sqrtf(ss + 1e-12f);
#pragma unroll
  for (int i = 0; i < DIM; i++) z[i] *= rz;

  int kbase = chunk * CPC;
  const float* ep = emb_n + (size_t)kbase * DIM;
  const float* nq = nsq + kbase;

  float best = 3.4e38f;
  int bidx = kbase;
  for (int k = 0; k < CPC; k += 4) {
    float d0 = 0.f, d1 = 0.f, d2 = 0.f, d3 = 0.f;
    const float* e0 = ep + (size_t)k * DIM;
#pragma unroll
    for (int i = 0; i < DIM; i++) {
      d0 = fmaf(z[i], e0[i], d0);
      d1 = fmaf(z[i], e0[DIM + i], d1);
      d2 = fmaf(z[i], e0[2 * DIM + i], d2);
      d3 = fmaf(z[i], e0[3 * DIM + i], d3);
    }
    float t0 = fmaf(d0, -2.f, nq[k]);
    float t1 = fmaf(d1, -2.f, nq[k + 1]);
    float t2 = fmaf(d2, -2.f, nq[k + 2]);
    float t3 = fmaf(d3, -2.f, nq[k + 3]);
    if (t0 < best) { best = t0; bidx = kbase + k; }
    if (t1 < best) { best = t1; bidx = kbase + k + 1; }
    if (t2 < best) { best = t2; bidx = kbase + k + 2; }
    if (t3 < best) { best = t3; bidx = kbase + k + 3; }
  }
  pdist[(size_t)token * CHUNKS + chunk] = best;
  pidx[(size_t)token * CHUNKS + chunk] = bidx;
}

// ---------------------------------------------------------------------------
// Kernel 3: reduce chunk partials -> final index; gather raw embedding row,
// normalize -> z_q; write index (as float); accumulate loss partials.
// ---------------------------------------------------------------------------
__global__ __launch_bounds__(256) void finalize_kernel(
    const float* __restrict__ hs, const float* __restrict__ emb,
    const float* __restrict__ pdist, const int* __restrict__ pidx,
    float* __restrict__ out, float* __restrict__ lossacc) {
  int token = blockIdx.x * 256 + threadIdx.x;

  float best = 3.4e38f;
  int bidx = 0;
#pragma unroll
  for (int c = 0; c < CHUNKS; c++) {
    float d = pdist[(size_t)token * CHUNKS + c];
    int i = pidx[(size_t)token * CHUNKS + c];
    if (d < best) { best = d; bidx = i; }  // chunks ascend in index order
  }
  out[(size_t)ZQ_ELEMS + token] = (float)bidx;

  // gather raw embedding row, normalize
  const float4* e = (const float4*)(emb + (size_t)bidx * DIM);
  float4 ev[8];
  float s = 0.f;
#pragma unroll
  for (int j = 0; j < 8; j++) {
    ev[j] = e[j];
    s += ev[j].x * ev[j].x + ev[j].y * ev[j].y + ev[j].z * ev[j].z +
         ev[j].w * ev[j].w;
  }
  float r = 1.0f / sqrtf(s + 1e-12f);

  // hidden_normed
  const float4* hp = (const float4*)(hs + (size_t)token * DIM);
  float4 hv[8];
  float ss = 0.f;
#pragma unroll
  for (int j = 0; j < 8; j++) {
    hv[j] = hp[j];
    ss += hv[j].x * hv[j].x + hv[j].y * hv[j].y + hv[j].z * hv[j].z +
          hv[j].w * hv[j].w;
  }
  float rz = 1.0f / sqrtf(ss + 1e-12f);

  float4* op = (float4*)(out + (size_t)token * DIM);
  float acc = 0.f;
#pragma unroll
  for (int j = 0; j < 8; j++) {
    float4 zq;
    zq.x = ev[j].x * r; zq.y = ev[j].y * r;
    zq.z = ev[j].z * r; zq.w = ev[j].w * r;
    op[j] = zq;
    float dx = zq.x - hv[j].x * rz;
    float dy = zq.y - hv[j].y * rz;
    float dz = zq.z - hv[j].z * rz;
    float dw = zq.w - hv[j].w * rz;
    acc += dx * dx + dy * dy + dz * dz + dw * dw;
  }

  // block-level reduction of loss partials
#pragma unroll
  for (int off = 32; off > 0; off >>= 1) acc += __shfl_xor(acc, off, 64);
  __shared__ float red[4];
  int wid = threadIdx.x >> 6;
  if ((threadIdx.x & 63) == 0) red[wid] = acc;
  __syncthreads();
  if (threadIdx.x == 0) {
    float b = red[0] + red[1] + red[2] + red[3];
    atomicAdd(lossacc, b);
  }
}

// ---------------------------------------------------------------------------
// Kernel 4: write the two (numerically identical) losses.
// ---------------------------------------------------------------------------
__global__ void loss_write_kernel(const float* __restrict__ lossacc,
                                  float* __restrict__ out) {
  float l = lossacc[0] * (1.0f / (float)ZQ_ELEMS);
  out[ZQ_ELEMS + TOKENS] = l;      // q_latent_loss
  out[ZQ_ELEMS + TOKENS + 1] = l;  // e_latent_loss
}

extern "C" void kernel_launch(void* const* d_in, const int* in_sizes, int n_in,
                              void* d_out, int out_size, void* d_ws,
                              size_t ws_size, hipStream_t stream) {
  const float* hs = (const float*)d_in[0];   // [32,1024,32]
  const float* emb = (const float*)d_in[1];  // [8192,32]
  float* out = (float*)d_out;
  char* ws = (char*)d_ws;

  float* emb_n = (float*)(ws);                                     // 1 MB
  float* nsq = (float*)(ws + 1048576);                             // 32 KB
  float* pdist = (float*)(ws + 1048576 + 32768);                   // 1 MB
  int* pidx = (int*)(ws + 1048576 + 32768 + 1048576);              // 1 MB
  float* lossacc = (float*)(ws + 1048576 + 32768 + 2 * 1048576);   // 4 B

  hipLaunchKernelGGL(norm_emb_kernel, dim3((KCODES * DIM) / 256), dim3(256), 0,
                     stream, emb, emb_n, nsq);
  hipLaunchKernelGGL(argmin_partial_kernel, dim3(TOKENS / 256, CHUNKS),
                     dim3(256), 0, stream, hs, emb_n, nsq, pdist, pidx);
  hipMemsetAsync(lossacc, 0, 4, stream);
  hipLaunchKernelGGL(finalize_kernel, dim3(TOKENS / 256), dim3(256), 0, stream,
                     hs, emb, pdist, pidx, out, lossacc);
  hipLaunchKernelGGL(loss_write_kernel, dim3(1), dim3(1), 0, stream, lossacc,
                     out);
}

// Round 2
// 102.130 us; speedup vs baseline: 3.7814x; 3.7814x over previous
//
#include <hip/hip_runtime.h>
#include <math.h>

#define TOKENS 32768
#define KCODES 8192
#define DIM 32
#define CHUNKS 8            // code chunks in grid-y
#define CPC (KCODES / CHUNKS)   // 1024 codes per chunk
#define ZQ_ELEMS (TOKENS * DIM)

typedef __attribute__((ext_vector_type(8))) short short8v;   // 8 bf16 = 4 VGPR
typedef __attribute__((ext_vector_type(4))) float f32x4;

// round-to-nearest-even float bits -> bf16 bits
__device__ inline unsigned rne16(unsigned u) {
  return (u + 0x7FFFu + ((u >> 16) & 1u)) >> 16;
}

// ---------------------------------------------------------------------------
// Kernel 1: preprocess codes.  e_n = l2_normalize(emb row); nsq = sum(e_n^2);
// w = -2*e_n split into 3 bf16 terms, stored in MFMA-A-fragment-linear layout:
//   element (code, k) -> tile=code>>4, lane=(code&15)|((k>>3)<<4), j=k&7
//   offset = tile*512 + lane*8 + j
// ---------------------------------------------------------------------------
__global__ __launch_bounds__(256) void prep_codes(
    const float* __restrict__ emb, short* __restrict__ cA,
    short* __restrict__ cB, short* __restrict__ cC, float* __restrict__ nsq) {
  int gid = blockIdx.x * 256 + threadIdx.x;  // 0..262143
  int code = gid >> 5;
  int k = gid & 31;
  float v = emb[gid];
  float s = v * v;
#pragma unroll
  for (int off = 16; off > 0; off >>= 1) s += __shfl_xor(s, off, 32);
  float r = 1.0f / sqrtf(s + 1e-12f);
  float en = v * r;
  float s2 = en * en;
#pragma unroll
  for (int off = 16; off > 0; off >>= 1) s2 += __shfl_xor(s2, off, 32);
  if (k == 0) nsq[code] = s2;

  float w = -2.0f * en;
  unsigned ua = rne16(__float_as_uint(w));
  float fa = __uint_as_float(ua << 16);
  float r1 = w - fa;
  unsigned ub = rne16(__float_as_uint(r1));
  float fb = __uint_as_float(ub << 16);
  float r2 = r1 - fb;
  unsigned uc = rne16(__float_as_uint(r2));

  int tile = code >> 4;
  int lane = (code & 15) | ((k >> 3) << 4);
  int off = tile * 512 + lane * 8 + (k & 7);
  cA[off] = (short)ua;
  cB[off] = (short)ub;
  cC[off] = (short)uc;
}

// ---------------------------------------------------------------------------
// Kernel 2: MFMA argmin.  Block = 4 waves x 64 tokens = 256 tokens.
// grid = (128 token-blocks, 8 code-chunks).  Each block scans 1024 codes in
// 8 LDS-staged sub-chunks of 128 codes (8 code-tiles each).
// Distance = nsq[k] + sum_i (-2 e_n)_i * z_n_i  via 6 split-term MFMAs with
// C initialized to nsq.  Per-lane running argmin over C rows, then shfl
// reduce over the lane>>4 groups with exact tie-break (smallest index).
// ---------------------------------------------------------------------------
__global__ __launch_bounds__(256) void argmin_mfma(
    const float* __restrict__ hs, const short* __restrict__ cA,
    const short* __restrict__ cB, const short* __restrict__ cC,
    const float* __restrict__ nsqG, float* __restrict__ pdist,
    int* __restrict__ pidx) {
  __shared__ short lA[4096];   // 8 KB: 8 code-tiles, term A
  __shared__ short lB[4096];
  __shared__ short lC[4096];
  __shared__ float lN[128];    // nsq sub-chunk

  int tid = threadIdx.x;
  int l = tid & 63;
  int w = tid >> 6;
  int g = l >> 4;
  int c16 = l & 15;

  int gt0 = blockIdx.x * 16 + w * 4;  // first global token-tile of this wave

  // --- build B-fragments for 4 token-tiles (normalize + bf16x3 split) ---
  short8v bA[4], bB[4], bC[4];
#pragma unroll
  for (int tt = 0; tt < 4; tt++) {
    int tok = (gt0 + tt) * 16 + c16;
    const float4* hp4 = (const float4*)(hs + (size_t)tok * DIM + g * 8);
    float4 q0 = hp4[0];
    float4 q1 = hp4[1];
    float x[8] = {q0.x, q0.y, q0.z, q0.w, q1.x, q1.y, q1.z, q1.w};
    float ss = 0.f;
#pragma unroll
    for (int j = 0; j < 8; j++) ss += x[j] * x[j];
    ss += __shfl_xor(ss, 16);
    ss += __shfl_xor(ss, 32);
    float rz = 1.0f / sqrtf(ss + 1e-12f);
#pragma unroll
    for (int j = 0; j < 8; j++) {
      float zn = x[j] * rz;
      unsigned ua = rne16(__float_as_uint(zn));
      float fa = __uint_as_float(ua << 16);
      float r1 = zn - fa;
      unsigned ub = rne16(__float_as_uint(r1));
      float fb = __uint_as_float(ub << 16);
      float r2 = r1 - fb;
      unsigned uc = rne16(__float_as_uint(r2));
      bA[tt][j] = (short)ua;
      bB[tt][j] = (short)ub;
      bC[tt][j] = (short)uc;
    }
  }

  float best[4] = {3.4e38f, 3.4e38f, 3.4e38f, 3.4e38f};
  int bidx[4] = {0, 0, 0, 0};
  int cbase = blockIdx.y * CPC;

  for (int s = 0; s < 8; s++) {
    __syncthreads();
    // stage 128 codes (8 tiles) of each term + nsq into LDS (linear copy)
    size_t eb = ((size_t)(cbase >> 4) + s * 8) * 512;  // element base
    const float4* sA = (const float4*)(cA + eb);
    const float4* sB = (const float4*)(cB + eb);
    const float4* sC = (const float4*)(cC + eb);
    ((float4*)lA)[tid] = sA[tid];
    ((float4*)lA)[tid + 256] = sA[tid + 256];
    ((float4*)lB)[tid] = sB[tid];
    ((float4*)lB)[tid + 256] = sB[tid + 256];
    ((float4*)lC)[tid] = sC[tid];
    ((float4*)lC)[tid + 256] = sC[tid + 256];
    if (tid < 128) lN[tid] = nsqG[cbase + s * 128 + tid];
    __syncthreads();

#pragma unroll
    for (int ct = 0; ct < 8; ct++) {
      f32x4 nv = *(const f32x4*)&lN[ct * 16 + g * 4];
      short8v aA = *(const short8v*)&lA[ct * 512 + l * 8];
      short8v aB = *(const short8v*)&lB[ct * 512 + l * 8];
      short8v aC = *(const short8v*)&lC[ct * 512 + l * 8];
      f32x4 acc[4];
      // 6 split terms, interleaved across the 4 token-tiles for MFMA ILP
#pragma unroll
      for (int tt = 0; tt < 4; tt++)
        acc[tt] = __builtin_amdgcn_mfma_f32_16x16x32_bf16(aA, bA[tt], nv, 0, 0, 0);
#pragma unroll
      for (int tt = 0; tt < 4; tt++)
        acc[tt] = __builtin_amdgcn_mfma_f32_16x16x32_bf16(aA, bB[tt], acc[tt], 0, 0, 0);
#pragma unroll
      for (int tt = 0; tt < 4; tt++)
        acc[tt] = __builtin_amdgcn_mfma_f32_16x16x32_bf16(aB, bA[tt], acc[tt], 0, 0, 0);
#pragma unroll
      for (int tt = 0; tt < 4; tt++)
        acc[tt] = __builtin_amdgcn_mfma_f32_16x16x32_bf16(aA, bC[tt], acc[tt], 0, 0, 0);
#pragma unroll
      for (int tt = 0; tt < 4; tt++)
        acc[tt] = __builtin_amdgcn_mfma_f32_16x16x32_bf16(aC, bA[tt], acc[tt], 0, 0, 0);
#pragma unroll
      for (int tt = 0; tt < 4; tt++)
        acc[tt] = __builtin_amdgcn_mfma_f32_16x16x32_bf16(aB, bB[tt], acc[tt], 0, 0, 0);

      int rb = cbase + s * 128 + ct * 16 + g * 4;  // this lane's code rows
#pragma unroll
      for (int tt = 0; tt < 4; tt++) {
#pragma unroll
        for (int r = 0; r < 4; r++) {
          float d = acc[tt][r];
          if (d < best[tt]) { best[tt] = d; bidx[tt] = rb + r; }
        }
      }
    }
  }

  // reduce across the 4 lane-groups (same token col, different code rows)
#pragma unroll
  for (int tt = 0; tt < 4; tt++) {
    {
      float od = __shfl_xor(best[tt], 16);
      int oi = __shfl_xor(bidx[tt], 16);
      if (od < best[tt] || (od == best[tt] && oi < bidx[tt])) {
        best[tt] = od; bidx[tt] = oi;
      }
    }
    {
      float od = __shfl_xor(best[tt], 32);
      int oi = __shfl_xor(bidx[tt], 32);
      if (od < best[tt] || (od == best[tt] && oi < bidx[tt])) {
        best[tt] = od; bidx[tt] = oi;
      }
    }
    if (l < 16) {
      int tok = (gt0 + tt) * 16 + c16;
      pdist[(size_t)tok * CHUNKS + blockIdx.y] = best[tt];
      pidx[(size_t)tok * CHUNKS + blockIdx.y] = bidx[tt];
    }
  }
}

// ---------------------------------------------------------------------------
// Kernel 3: reduce chunk partials -> final index; gather raw embedding row,
// normalize -> z_q; write index (as float); accumulate loss partials.
// ---------------------------------------------------------------------------
__global__ __launch_bounds__(256) void finalize_kernel(
    const float* __restrict__ hs, const float* __restrict__ emb,
    const float* __restrict__ pdist, const int* __restrict__ pidx,
    float* __restrict__ out, float* __restrict__ lossacc) {
  int token = blockIdx.x * 256 + threadIdx.x;

  float best = 3.4e38f;
  int bidx = 0;
#pragma unroll
  for (int c = 0; c < CHUNKS; c++) {
    float d = pdist[(size_t)token * CHUNKS + c];
    int i = pidx[(size_t)token * CHUNKS + c];
    if (d < best || (d == best && i < bidx)) { best = d; bidx = i; }
  }
  out[(size_t)ZQ_ELEMS + token] = (float)bidx;

  const float4* e = (const float4*)(emb + (size_t)bidx * DIM);
  float4 ev[8];
  float s = 0.f;
#pragma unroll
  for (int j = 0; j < 8; j++) {
    ev[j] = e[j];
    s += ev[j].x * ev[j].x + ev[j].y * ev[j].y + ev[j].z * ev[j].z +
         ev[j].w * ev[j].w;
  }
  float r = 1.0f / sqrtf(s + 1e-12f);

  const float4* hp = (const float4*)(hs + (size_t)token * DIM);
  float4 hv[8];
  float ss = 0.f;
#pragma unroll
  for (int j = 0; j < 8; j++) {
    hv[j] = hp[j];
    ss += hv[j].x * hv[j].x + hv[j].y * hv[j].y + hv[j].z * hv[j].z +
          hv[j].w * hv[j].w;
  }
  float rz = 1.0f / sqrtf(ss + 1e-12f);

  float4* op = (float4*)(out + (size_t)token * DIM);
  float acc = 0.f;
#pragma unroll
  for (int j = 0; j < 8; j++) {
    float4 zq;
    zq.x = ev[j].x * r; zq.y = ev[j].y * r;
    zq.z = ev[j].z * r; zq.w = ev[j].w * r;
    op[j] = zq;
    float dx = zq.x - hv[j].x * rz;
    float dy = zq.y - hv[j].y * rz;
    float dz = zq.z - hv[j].z * rz;
    float dw = zq.w - hv[j].w * rz;
    acc += dx * dx + dy * dy + dz * dz + dw * dw;
  }

#pragma unroll
  for (int off = 32; off > 0; off >>= 1) acc += __shfl_xor(acc, off, 64);
  __shared__ float red[4];
  int wid = threadIdx.x >> 6;
  if ((threadIdx.x & 63) == 0) red[wid] = acc;
  __syncthreads();
  if (threadIdx.x == 0) {
    float b = red[0] + red[1] + red[2] + red[3];
    atomicAdd(lossacc, b);
  }
}

__global__ void loss_write_kernel(const float* __restrict__ lossacc,
                                  float* __restrict__ out) {
  float l = lossacc[0] * (1.0f / (float)ZQ_ELEMS);
  out[ZQ_ELEMS + TOKENS] = l;      // q_latent_loss
  out[ZQ_ELEMS + TOKENS + 1] = l;  // e_latent_loss
}

extern "C" void kernel_launch(void* const* d_in, const int* in_sizes, int n_in,
                              void* d_out, int out_size, void* d_ws,
                              size_t ws_size, hipStream_t stream) {
  const float* hs = (const float*)d_in[0];   // [32,1024,32]
  const float* emb = (const float*)d_in[1];  // [8192,32]
  float* out = (float*)d_out;
  char* ws = (char*)d_ws;

  short* cA = (short*)(ws);                         // 512 KB
  short* cB = (short*)(ws + 524288);                // 512 KB
  short* cC = (short*)(ws + 1048576);               // 512 KB
  float* nsq = (float*)(ws + 1572864);              // 32 KB
  float* pdist = (float*)(ws + 1605632);            // 1 MB
  int* pidx = (int*)(ws + 2654208);                 // 1 MB
  float* lossacc = (float*)(ws + 3702784);          // 4 B

  hipLaunchKernelGGL(prep_codes, dim3((KCODES * DIM) / 256), dim3(256), 0,
                     stream, emb, cA, cB, cC, nsq);
  hipLaunchKernelGGL(argmin_mfma, dim3(TOKENS / 256, CHUNKS), dim3(256), 0,
                     stream, hs, cA, cB, cC, nsq, pdist, pidx);
  hipMemsetAsync(lossacc, 0, 4, stream);
  hipLaunchKernelGGL(finalize_kernel, dim3(TOKENS / 256), dim3(256), 0, stream,
                     hs, emb, pdist, pidx, out, lossacc);
  hipLaunchKernelGGL(loss_write_kernel, dim3(1), dim3(1), 0, stream, lossacc,
                     out);
}